// Round 2
// baseline (9632.430 us; speedup 1.0000x reference)
//
#include <hip/hip_runtime.h>
#include <stdint.h>

#define BATCH 4
#define NPTS  8192
#define CFEAT 64
#define MCENT 2048
#define NCENT (BATCH * MCENT)
#define KMAX  64
#define NEGV  -1e30f

// Exact-rounding squared distance, matching numpy's ((dx*dx+dy*dy)+dz*dz)
// with NO fma contraction (discrete neighbor selection requires bit parity).
__device__ __forceinline__ float dist2(float ax, float ay, float az,
                                       float bx, float by, float bz) {
    float dx = __fsub_rn(ax, bx);
    float dy = __fsub_rn(ay, by);
    float dz = __fsub_rn(az, bz);
    return __fadd_rn(__fadd_rn(__fmul_rn(dx, dx), __fmul_rn(dy, dy)),
                     __fmul_rn(dz, dz));
}

// DPP lane-permute helpers (VALU-latency cross-lane, vs ds_bpermute ~120cyc)
template <int CTRL>
__device__ __forceinline__ float dppf(float v) {
    return __int_as_float(__builtin_amdgcn_update_dpp(
        __float_as_int(v), __float_as_int(v), CTRL, 0xF, 0xF, false));
}
template <int CTRL>
__device__ __forceinline__ int dppi(int v) {
    return __builtin_amdgcn_update_dpp(v, v, CTRL, 0xF, 0xF, false);
}

// ---------------------------------------------------------------------------
// Kernel 1: farthest point sampling, multi-CU.
//
// Round-5 post-mortem: LDS staging was a null (2899us == 2860us) — FETCH was
// always ~210KB (L1-warm reloads), never the bottleneck. The real profile:
// per-CU VALU ~65% busy, ~3400cy/iter on only 4 CUs (8192 dist comps / 8
// waves) + ~1200cy argmax tail (DPP+LDS+barrier+scan+broadcast).
//
// Fix: 64 waves per batch across 8 blocks (32 blocks total). Each wave owns
// 128 points (2/thread, pinned in registers via asm). Sync via 64 global u64
// key slots per batch per parity: key = (tag=m+1 | d2 bits | 8191-p). The
// key is self-contained -> relaxed agent-scope atomics, no fences. Parity
// double-buffer + tag makes overwrite races impossible (a wave is >=2 full
// combines behind before its slot can be overwritten). Winner coords re-read
// from read-only pos[] (always coherent). No __syncthreads in the loop.
// Key max order == argmax first-max semantics (value bits monotone for
// nonneg floats; invp tie -> min index). Poll cap turns any residency
// pathology into a visible wrong answer, not a hang.
// ---------------------------------------------------------------------------
#define FPS_BLOCKS 32
#define FPS_T      512

__global__ __launch_bounds__(FPS_T, 2) void fps_kernel(
        const float* __restrict__ pos, float* __restrict__ pos_s,
        unsigned long long* __restrict__ slots) {
    const int blk  = blockIdx.x;
    const int b    = blk & 3;           // batch
    const int g    = blk >> 2;          // block group 0..7 within batch
    const int t    = threadIdx.x;
    const int wv   = (g << 3) + (t >> 6);   // wave id within batch, 0..63
    const int lane = t & 63;
    const float* pb = pos + b * NPTS * 3;
    const bool leader = (g == 0) && (t == 0);

    // two points per thread, pinned in registers (opaque to remat)
    const int p0 = (wv << 7) + lane;
    const int p1 = p0 + 64;
    float px0 = pb[3 * p0 + 0], py0 = pb[3 * p0 + 1], pz0 = pb[3 * p0 + 2];
    float px1 = pb[3 * p1 + 0], py1 = pb[3 * p1 + 1], pz1 = pb[3 * p1 + 2];
    asm volatile("" : "+v"(px0), "+v"(py0), "+v"(pz0),
                      "+v"(px1), "+v"(py1), "+v"(pz1));
    float mind0 = 1e30f, mind1 = 1e30f;

    // slots layout: [parity][batch][64]
    unsigned long long* sl = slots + (size_t)b * 64;

    float lx = pb[0], ly = pb[1], lz = pb[2];   // first centroid = point 0

    for (int m = 0; m < MCENT; ++m) {
        if (leader) {
            float* o = pos_s + (b * MCENT + m) * 3;
            o[0] = lx; o[1] = ly; o[2] = lz;
        }
        if (m + 1 == MCENT) break;      // final argmax discarded by the scan

        // update mind; thread-level argmax (tie -> lower index p0)
        float d0 = dist2(px0, py0, pz0, lx, ly, lz);
        float d1 = dist2(px1, py1, pz1, lx, ly, lz);
        mind0 = fminf(mind0, d0);
        mind1 = fminf(mind1, d1);
        float bv; int bp;
        if (mind0 >= mind1) { bv = mind0; bp = p0; }
        else                { bv = mind1; bp = p1; }

        // wave argmax to lane 63 via DPP absorb chain (max, tie -> min idx)
#define RSTEP(C_) { float ov = dppf<C_>(bv); int op_ = dppi<C_>(bp);          \
                    bool tk = (ov > bv) || (ov == bv && op_ < bp);            \
                    bv = tk ? ov : bv; bp = tk ? op_ : bp; }
        RSTEP(0xB1)   // quad_perm xor1
        RSTEP(0x4E)   // quad_perm xor2
        RSTEP(0x141)  // row_half_mirror xor4
        RSTEP(0x140)  // row_mirror xor8
        RSTEP(0x142)  // row_bcast15
        RSTEP(0x143)  // row_bcast31  -> lane63 holds wave winner
#undef RSTEP

        const unsigned int want = (unsigned int)(m + 1);
        unsigned long long* psl = sl + ((m & 1) ? (size_t)(4 * 64) : 0);

        if (lane == 63) {
            unsigned long long key =
                ((unsigned long long)want << 45) |
                ((unsigned long long)__float_as_uint(bv) << 13) |
                (unsigned long long)(8191 - bp);
            __hip_atomic_store(&psl[wv], key, __ATOMIC_RELAXED,
                               __HIP_MEMORY_SCOPE_AGENT);
        }

        // each lane polls one slot until its tag arrives (cap -> no hang)
        unsigned long long k;
        int tries = 0;
        do {
            k = __hip_atomic_load(&psl[lane], __ATOMIC_RELAXED,
                                  __HIP_MEMORY_SCOPE_AGENT);
        } while ((unsigned int)(k >> 45) != want && ++tries < (1 << 20));

        // wave max-reduce of 64 keys to lane 63 (u64 compare: tag equal,
        // then d2 bits, then invp -> min index)
#define KSTEP(C_) { int klo = dppi<C_>((int)(unsigned int)k);                 \
                    int khi = dppi<C_>((int)(unsigned int)(k >> 32));         \
                    unsigned long long ok =                                    \
                        ((unsigned long long)(unsigned int)khi << 32) |        \
                        (unsigned int)klo;                                     \
                    k = ok > k ? ok : k; }
        KSTEP(0xB1)
        KSTEP(0x4E)
        KSTEP(0x141)
        KSTEP(0x140)
        KSTEP(0x142)
        KSTEP(0x143)
#undef KSTEP

        int gp = 8191 - (int)(k & 0x1FFFULL);
        gp = __builtin_amdgcn_readlane(gp, 63);     // broadcast winner index
        lx = pb[3 * gp + 0];                        // read-only: coherent
        ly = pb[3 * gp + 1];
        lz = pb[3 * gp + 2];
    }
}

// ---------------------------------------------------------------------------
// Kernel 2: exact top-64 (by (d2, idx) u64 key) within ball r=0.4 via
// histogram radix-select + O(C^2) exact ranking. Downstream max-aggregation
// is order-invariant, but ranks reproduce lax.top_k order anyway.
// ---------------------------------------------------------------------------
#define KNN_CAP 320

__global__ __launch_bounds__(256) void knn_kernel(const float* __restrict__ pos,
                                                  const float* __restrict__ pos_s,
                                                  int* __restrict__ nidx,
                                                  float* __restrict__ nd2,
                                                  int* __restrict__ ncnt) {
    const int c = blockIdx.x;
    const int b = c >> 11;              // c / MCENT
    const float* pb = pos + b * NPTS * 3;
    const int t = threadIdx.x;

    const float cx = pos_s[c * 3 + 0];
    const float cy = pos_s[c * 3 + 1];
    const float cz = pos_s[c * 3 + 2];

    __shared__ int hist[64];
    __shared__ int s_B64, s_total, s_cnt;
    __shared__ unsigned long long cand[KNN_CAP];

    if (t < 64) hist[t] = 0;
    if (t == 0) s_cnt = 0;
    __syncthreads();

    float d2r[32];
#pragma unroll
    for (int i = 0; i < 32; ++i) {
        int p = (i << 8) + t;
        float d2 = dist2(cx, cy, cz, pb[3 * p + 0], pb[3 * p + 1], pb[3 * p + 2]);
        d2r[i] = d2;
        if (d2 <= 0.16f) {
            int bkt = (int)(d2 * 400.0f);      // monotone; 0.16f*400 < 64
            bkt = bkt > 63 ? 63 : bkt;
            atomicAdd(&hist[bkt], 1);
        }
    }
    __syncthreads();

    if (t == 0) {
        int cum = 0, B = -1;
#pragma unroll
        for (int j = 0; j < 64; ++j) {
            cum += hist[j];
            if (B < 0 && cum >= 64) B = j;
        }
        s_B64 = (B < 0) ? 63 : B;
        s_total = cum;
    }
    __syncthreads();

    const int B64 = s_B64;
#pragma unroll
    for (int i = 0; i < 32; ++i) {
        float d2 = d2r[i];
        if (d2 <= 0.16f) {
            int bkt = (int)(d2 * 400.0f);
            bkt = bkt > 63 ? 63 : bkt;
            if (bkt <= B64) {
                int slot = atomicAdd(&s_cnt, 1);
                if (slot < KNN_CAP) {
                    int p = (i << 8) + t;
                    cand[slot] = ((unsigned long long)__float_as_uint(d2) << 32)
                                 | (unsigned int)p;
                }
            }
        }
    }
    __syncthreads();

    const int C = s_cnt < KNN_CAP ? s_cnt : KNN_CAP;
    // exact rank: candidate set is downward-closed, so candidate rank ==
    // global in-ball rank. Broadcast LDS reads (wave-uniform j).
    for (int tc = t; tc < C; tc += 256) {
        unsigned long long my = cand[tc];
        int rank = 0;
        for (int j = 0; j < C; ++j) rank += (cand[j] < my) ? 1 : 0;
        if (rank < KMAX) {
            nidx[c * KMAX + rank] = (int)(my & 0xffffffffULL);
            nd2[c * KMAX + rank]  = __uint_as_float((unsigned int)(my >> 32));
        }
    }
    if (t == 0) ncnt[c] = s_total < KMAX ? s_total : KMAX;
}

// ---------------------------------------------------------------------------
// Kernel 3: fused gather + 2-layer MLP + masked max per centroid.
// ---------------------------------------------------------------------------
template <int K, int C1, int C2, int OUTOFF>
__global__ __launch_bounds__(256, 2) void mlp_kernel(
        const float* __restrict__ x, const float* __restrict__ pos,
        const float* __restrict__ pos_s,
        const int* __restrict__ nidx, const float* __restrict__ nd2,
        const int* __restrict__ ncnt,
        const float* __restrict__ W1, const float* __restrict__ B1,
        const float* __restrict__ W2, const float* __restrict__ B2,
        float* __restrict__ out, float r2) {
    const int c = blockIdx.x;
    const int b = c >> 11;
    const int t = threadIdx.x;

    __shared__ float F[K][68];      // [K][67] padded to 17 float4
    __shared__ float H[K][C1];
    __shared__ int   s_nbr[K];
    __shared__ int   s_valid[K];
    __shared__ float s_ctr[3];

    const int cntAll = ncnt[c];
    const int cnt = cntAll < K ? cntAll : K;
    if (t < 3) s_ctr[t] = pos_s[c * 3 + t];
    if (t < K) {
        bool ok = t < cnt;
        s_nbr[t]   = ok ? nidx[c * KMAX + t] : 0;
        s_valid[t] = ok && (nd2[c * KMAX + t] <= r2);
    }
    __syncthreads();

    // gather features: F[k] = [ x[nbr] (64) | pos[nbr]-ctr (3) | 0 pad ]
    for (int e = t; e < K * 17; e += 256) {
        int k = e / 17, q = e % 17;
        int nbr = s_nbr[k];
        bool ok = k < cnt;
        float4 val;
        if (q < 16) {
            const float4* xr = (const float4*)(x + (b * NPTS + nbr) * CFEAT);
            if (ok) val = xr[q];
            else { val.x = 0.f; val.y = 0.f; val.z = 0.f; val.w = 0.f; }
        } else {
            const float* pp = pos + (b * NPTS + nbr) * 3;
            val.x = ok ? pp[0] - s_ctr[0] : 0.f;
            val.y = ok ? pp[1] - s_ctr[1] : 0.f;
            val.z = ok ? pp[2] - s_ctr[2] : 0.f;
            val.w = 0.f;
        }
        ((float4*)&F[k][0])[q] = val;
    }
    __syncthreads();

    // layer 1: H[k][j] = relu(B1[j] + F[k]·W1[:,j])
    {
        constexpr int STR = 256 / C1;
        const int j  = t % C1;
        const int kb = t / C1;
        float w1c[68];
#pragma unroll
        for (int i = 0; i < 67; ++i) w1c[i] = W1[i * C1 + j];
        w1c[67] = 0.f;
        const float bj = B1[j];
        for (int k = kb; k < K; k += STR) {
            float acc = bj;
            const float4* fr = (const float4*)&F[k][0];
#pragma unroll
            for (int q = 0; q < 17; ++q) {
                float4 f = fr[q];
                acc = fmaf(f.x, w1c[4 * q + 0], acc);
                acc = fmaf(f.y, w1c[4 * q + 1], acc);
                acc = fmaf(f.z, w1c[4 * q + 2], acc);
                acc = fmaf(f.w, w1c[4 * q + 3], acc);
            }
            H[k][j] = fmaxf(acc, 0.f);
        }
    }
    __syncthreads();

    // layer 2 + masked max over neighbors
    if constexpr (C2 == 256) {
        const int j2 = t;
        float w2c[C1];
#pragma unroll
        for (int i = 0; i < C1; ++i) w2c[i] = W2[i * C2 + j2];
        const float bj = B2[j2];
        float omax = NEGV;
        for (int k = 0; k < K; ++k) {
            if (!s_valid[k]) continue;          // uniform branch
            float acc = bj;
            const float4* hr = (const float4*)&H[k][0];
#pragma unroll
            for (int q = 0; q < C1 / 4; ++q) {
                float4 h = hr[q];
                acc = fmaf(h.x, w2c[4 * q + 0], acc);
                acc = fmaf(h.y, w2c[4 * q + 1], acc);
                acc = fmaf(h.z, w2c[4 * q + 2], acc);
                acc = fmaf(h.w, w2c[4 * q + 3], acc);
            }
            omax = fmaxf(omax, fmaxf(acc, 0.f));
        }
        out[c * 384 + OUTOFF + j2] = omax;
    } else {
        // C2 == 128: 2 thread-groups split the k range, combine via LDS
        const int j2 = t % C2;
        const int g  = t / C2;
        __shared__ float pm[256];
        float w2c[C1];
#pragma unroll
        for (int i = 0; i < C1; ++i) w2c[i] = W2[i * C2 + j2];
        const float bj = B2[j2];
        float omax = NEGV;
        for (int k = g; k < K; k += 2) {
            if (!s_valid[k]) continue;
            float acc = bj;
            const float4* hr = (const float4*)&H[k][0];
#pragma unroll
            for (int q = 0; q < C1 / 4; ++q) {
                float4 h = hr[q];
                acc = fmaf(h.x, w2c[4 * q + 0], acc);
                acc = fmaf(h.y, w2c[4 * q + 1], acc);
                acc = fmaf(h.z, w2c[4 * q + 2], acc);
                acc = fmaf(h.w, w2c[4 * q + 3], acc);
            }
            omax = fmaxf(omax, fmaxf(acc, 0.f));
        }
        pm[t] = omax;
        __syncthreads();
        if (t < C2) out[c * 384 + OUTOFF + t] = fmaxf(pm[t], pm[t + C2]);
    }
}

extern "C" void kernel_launch(void* const* d_in, const int* in_sizes, int n_in,
                              void* d_out, int out_size, void* d_ws, size_t ws_size,
                              hipStream_t stream) {
    const float* x    = (const float*)d_in[0];
    const float* pos  = (const float*)d_in[1];
    const float* w1_0 = (const float*)d_in[2];
    const float* b1_0 = (const float*)d_in[3];
    const float* w1_1 = (const float*)d_in[4];
    const float* b1_1 = (const float*)d_in[5];
    const float* w2_0 = (const float*)d_in[6];
    const float* b2_0 = (const float*)d_in[7];
    const float* w2_1 = (const float*)d_in[8];
    const float* b2_1 = (const float*)d_in[9];

    float* out   = (float*)d_out;
    float* pos_s = out + NCENT * 384;          // second output, written by FPS

    char* ws = (char*)d_ws;
    unsigned long long* slots = (unsigned long long*)ws;      // [2][4][64] = 4KB
    int*   ncnt = (int*)(ws + 4096);                          // NCENT ints
    int*   nidx = (int*)(ws + 4096 + NCENT * 4);              // NCENT*64 ints
    float* nd2  = (float*)(ws + 4096 + NCENT * 4 + NCENT * KMAX * 4);

    hipMemsetAsync(slots, 0, 2 * 4 * 64 * sizeof(unsigned long long), stream);
    fps_kernel<<<FPS_BLOCKS, FPS_T, 0, stream>>>(pos, pos_s, slots);
    knn_kernel<<<NCENT, 256, 0, stream>>>(pos, pos_s, nidx, nd2, ncnt);
    mlp_kernel<32, 64, 128, 0><<<NCENT, 256, 0, stream>>>(
        x, pos, pos_s, nidx, nd2, ncnt, w1_0, b1_0, w1_1, b1_1, out, 0.04f);
    mlp_kernel<64, 128, 256, 128><<<NCENT, 256, 0, stream>>>(
        x, pos, pos_s, nidx, nd2, ncnt, w2_0, b2_0, w2_1, b2_1, out, 0.16f);
}

// Round 3
// 2992.034 us; speedup vs baseline: 3.2194x; 3.2194x over previous
//
#include <hip/hip_runtime.h>
#include <stdint.h>

#define BATCH 4
#define NPTS  8192
#define CFEAT 64
#define MCENT 2048
#define NCENT (BATCH * MCENT)
#define KMAX  64
#define NEGV  -1e30f

// Exact-rounding squared distance, matching numpy's ((dx*dx+dy*dy)+dz*dz)
// with NO fma contraction (discrete neighbor selection requires bit parity).
__device__ __forceinline__ float dist2(float ax, float ay, float az,
                                       float bx, float by, float bz) {
    float dx = __fsub_rn(ax, bx);
    float dy = __fsub_rn(ay, by);
    float dz = __fsub_rn(az, bz);
    return __fadd_rn(__fadd_rn(__fmul_rn(dx, dx), __fmul_rn(dy, dy)),
                     __fmul_rn(dz, dz));
}

template <int CTRL>
__device__ __forceinline__ int dppi(int v) {
    return __builtin_amdgcn_update_dpp(v, v, CTRL, 0xF, 0xF, false);
}

// u64 max-combine with a DPP lane permute (lo/hi words permuted separately).
#define KSTEP(k, C_) { int klo_ = dppi<C_>((int)(unsigned int)(k));           \
                       int khi_ = dppi<C_>((int)(unsigned int)((k) >> 32));   \
                       unsigned long long ok_ =                               \
                           ((unsigned long long)(unsigned int)khi_ << 32) |   \
                           (unsigned int)klo_;                                \
                       (k) = ok_ > (k) ? ok_ : (k); }

// ---------------------------------------------------------------------------
// Kernel 1: farthest point sampling. One block per batch, 512 threads,
// 16 points per thread.
//
// Round-6 post-mortem chain:
//  * r0 (registers, no pin): LLVM remats point loads -> reload every iter.
//  * r1 (LDS-staged): null. Re-reading 16 pts/thread/iter = 256 DS ops/CU
//    ~1500cy/iter on the SHARED per-CU LDS pipe — co-bottleneck with VALU.
//  * r2 (multi-CU, global spin): catastrophic (LLC round-trip polling).
// This version: points pinned in REGISTERS via asm (opaque to remat — the
// asm result cannot be recomputed, so the allocator must keep it live).
// Zero loads of any kind in the distance phase. LDS keeps a copy only for
// the winner-coords broadcast (2 DS reads/iter) + final pos_s writeback.
// Cross-wave argmax: u64 key = (d2bits<<13 | 8191-p); lane63 of each wave
// writes its key; one ds_read_b64 + 3-step DPP butterfly (xor1/xor2/mirror8
// covers the 8-slot period) replaces the serial 8-entry scan. pos_s stores
// deferred to a bulk writeback (loop body has zero VMEM ops).
// ---------------------------------------------------------------------------
#define FPS_T   512
#define FPS_W   (FPS_T / 64)

#define REP16(X) X(0) X(1) X(2) X(3) X(4) X(5) X(6) X(7) \
                 X(8) X(9) X(10) X(11) X(12) X(13) X(14) X(15)

__global__ __launch_bounds__(FPS_T, 2) void fps_kernel(const float* __restrict__ pos,
                                                       float* __restrict__ pos_s) {
    const int b = blockIdx.x;
    const float* pb = pos + b * NPTS * 3;
    const int t = threadIdx.x;          // 0..511
    const int w = t >> 6;               // wave id 0..7
    const int lane = t & 63;

    __shared__ float2 sxy[NPTS];        // 64 KB (winner broadcast + writeback)
    __shared__ float  sz[NPTS];         // 32 KB
    __shared__ unsigned long long s_key[2][FPS_W];
    __shared__ int    s_win[MCENT];     // 8 KB winner indices

#define FPS_DECL(i) float px##i, py##i, pz##i, mind##i;
    REP16(FPS_DECL)
#undef FPS_DECL

    // load each point once: into pinned registers AND the LDS copy
#define FPS_LOAD(i) { int p = (i << 9) + t;                                   \
                      px##i = pb[3 * p + 0];                                  \
                      py##i = pb[3 * p + 1];                                  \
                      pz##i = pb[3 * p + 2];                                  \
                      float2 xy_; xy_.x = px##i; xy_.y = py##i;               \
                      sxy[p] = xy_;  sz[p] = pz##i;                           \
                      mind##i = 1e30f;                                        \
                      asm volatile("" : "+v"(px##i), "+v"(py##i), "+v"(pz##i)); }
    REP16(FPS_LOAD)
#undef FPS_LOAD

    if (t == 0) s_win[0] = 0;           // first centroid = point 0
    __syncthreads();

    float lx = sxy[0].x, ly = sxy[0].y, lz = sz[0];

    for (int m = 0; m < MCENT - 1; ++m) {
        // update mind, thread-local argmax over the 16 slots (i ascending ==
        // point index ascending for fixed t; strict > keeps lowest index).
        float bv = -1.0f; int bi = 0;
#define FPS_UPD(i) { float d = dist2(px##i, py##i, pz##i, lx, ly, lz);        \
                     float mn = fminf(mind##i, d);                            \
                     mind##i = mn;                                            \
                     bool tk = mn > bv;                                       \
                     bv = tk ? mn : bv;                                       \
                     bi = tk ? i : bi; }
        REP16(FPS_UPD)
#undef FPS_UPD
        int bp = (bi << 9) + t;

        // pack (d2, min-index) into one u64: bits monotone for nonneg floats,
        // invp tie-break -> min global index (validated bit-exact in r2).
        unsigned long long key =
            ((unsigned long long)__float_as_uint(bv) << 13) |
            (unsigned int)(8191 - bp);

        // wave reduce to lane 63 (absorb chain, idempotent u64 max)
        KSTEP(key, 0xB1)    // quad_perm xor1
        KSTEP(key, 0x4E)    // quad_perm xor2
        KSTEP(key, 0x141)   // row_half_mirror
        KSTEP(key, 0x140)   // row_mirror
        KSTEP(key, 0x142)   // row_bcast15
        KSTEP(key, 0x143)   // row_bcast31 -> lane63 holds wave winner

        const int par = m & 1;
        if (lane == 63) s_key[par][w] = key;
        __syncthreads();

        // every thread: one b64 read of slot (t&7), then 3-step butterfly.
        // Pattern has period 8; xor1+xor2 combine quads, mirror8 merges the
        // two quad-halves -> all lanes hold the global max.
        unsigned long long k = s_key[par][t & 7];
        KSTEP(k, 0xB1)
        KSTEP(k, 0x4E)
        KSTEP(k, 0x141)

        int gp = 8191 - (int)(k & 0x1FFFULL);
        if (t == 0) s_win[m + 1] = gp;
        float2 cxy = sxy[gp];            // broadcast LDS read (same addr)
        lx = cxy.x; ly = cxy.y; lz = sz[gp];
    }

    // bulk pos_s writeback (the only global stores in the kernel)
    __syncthreads();
    for (int m = t; m < MCENT; m += FPS_T) {
        int gp = s_win[m];
        float2 xy = sxy[gp]; float z = sz[gp];
        float* o = pos_s + (b * MCENT + m) * 3;
        o[0] = xy.x; o[1] = xy.y; o[2] = z;
    }
}
#undef KSTEP

// ---------------------------------------------------------------------------
// Kernel 2: exact top-64 (by (d2, idx) u64 key) within ball r=0.4 via
// histogram radix-select + O(C^2) exact ranking. Downstream max-aggregation
// is order-invariant, but ranks reproduce lax.top_k order anyway.
// ---------------------------------------------------------------------------
#define KNN_CAP 320

__global__ __launch_bounds__(256) void knn_kernel(const float* __restrict__ pos,
                                                  const float* __restrict__ pos_s,
                                                  int* __restrict__ nidx,
                                                  float* __restrict__ nd2,
                                                  int* __restrict__ ncnt) {
    const int c = blockIdx.x;
    const int b = c >> 11;              // c / MCENT
    const float* pb = pos + b * NPTS * 3;
    const int t = threadIdx.x;

    const float cx = pos_s[c * 3 + 0];
    const float cy = pos_s[c * 3 + 1];
    const float cz = pos_s[c * 3 + 2];

    __shared__ int hist[64];
    __shared__ int s_B64, s_total, s_cnt;
    __shared__ unsigned long long cand[KNN_CAP];

    if (t < 64) hist[t] = 0;
    if (t == 0) s_cnt = 0;
    __syncthreads();

    float d2r[32];
#pragma unroll
    for (int i = 0; i < 32; ++i) {
        int p = (i << 8) + t;
        float d2 = dist2(cx, cy, cz, pb[3 * p + 0], pb[3 * p + 1], pb[3 * p + 2]);
        d2r[i] = d2;
        if (d2 <= 0.16f) {
            int bkt = (int)(d2 * 400.0f);      // monotone; 0.16f*400 < 64
            bkt = bkt > 63 ? 63 : bkt;
            atomicAdd(&hist[bkt], 1);
        }
    }
    __syncthreads();

    if (t == 0) {
        int cum = 0, B = -1;
#pragma unroll
        for (int j = 0; j < 64; ++j) {
            cum += hist[j];
            if (B < 0 && cum >= 64) B = j;
        }
        s_B64 = (B < 0) ? 63 : B;
        s_total = cum;
    }
    __syncthreads();

    const int B64 = s_B64;
#pragma unroll
    for (int i = 0; i < 32; ++i) {
        float d2 = d2r[i];
        if (d2 <= 0.16f) {
            int bkt = (int)(d2 * 400.0f);
            bkt = bkt > 63 ? 63 : bkt;
            if (bkt <= B64) {
                int slot = atomicAdd(&s_cnt, 1);
                if (slot < KNN_CAP) {
                    int p = (i << 8) + t;
                    cand[slot] = ((unsigned long long)__float_as_uint(d2) << 32)
                                 | (unsigned int)p;
                }
            }
        }
    }
    __syncthreads();

    const int C = s_cnt < KNN_CAP ? s_cnt : KNN_CAP;
    // exact rank: candidate set is downward-closed, so candidate rank ==
    // global in-ball rank. Broadcast LDS reads (wave-uniform j).
    for (int tc = t; tc < C; tc += 256) {
        unsigned long long my = cand[tc];
        int rank = 0;
        for (int j = 0; j < C; ++j) rank += (cand[j] < my) ? 1 : 0;
        if (rank < KMAX) {
            nidx[c * KMAX + rank] = (int)(my & 0xffffffffULL);
            nd2[c * KMAX + rank]  = __uint_as_float((unsigned int)(my >> 32));
        }
    }
    if (t == 0) ncnt[c] = s_total < KMAX ? s_total : KMAX;
}

// ---------------------------------------------------------------------------
// Kernel 3: fused gather + 2-layer MLP + masked max per centroid.
// ---------------------------------------------------------------------------
template <int K, int C1, int C2, int OUTOFF>
__global__ __launch_bounds__(256, 2) void mlp_kernel(
        const float* __restrict__ x, const float* __restrict__ pos,
        const float* __restrict__ pos_s,
        const int* __restrict__ nidx, const float* __restrict__ nd2,
        const int* __restrict__ ncnt,
        const float* __restrict__ W1, const float* __restrict__ B1,
        const float* __restrict__ W2, const float* __restrict__ B2,
        float* __restrict__ out, float r2) {
    const int c = blockIdx.x;
    const int b = c >> 11;
    const int t = threadIdx.x;

    __shared__ float F[K][68];      // [K][67] padded to 17 float4
    __shared__ float H[K][C1];
    __shared__ int   s_nbr[K];
    __shared__ int   s_valid[K];
    __shared__ float s_ctr[3];

    const int cntAll = ncnt[c];
    const int cnt = cntAll < K ? cntAll : K;
    if (t < 3) s_ctr[t] = pos_s[c * 3 + t];
    if (t < K) {
        bool ok = t < cnt;
        s_nbr[t]   = ok ? nidx[c * KMAX + t] : 0;
        s_valid[t] = ok && (nd2[c * KMAX + t] <= r2);
    }
    __syncthreads();

    // gather features: F[k] = [ x[nbr] (64) | pos[nbr]-ctr (3) | 0 pad ]
    for (int e = t; e < K * 17; e += 256) {
        int k = e / 17, q = e % 17;
        int nbr = s_nbr[k];
        bool ok = k < cnt;
        float4 val;
        if (q < 16) {
            const float4* xr = (const float4*)(x + (b * NPTS + nbr) * CFEAT);
            if (ok) val = xr[q];
            else { val.x = 0.f; val.y = 0.f; val.z = 0.f; val.w = 0.f; }
        } else {
            const float* pp = pos + (b * NPTS + nbr) * 3;
            val.x = ok ? pp[0] - s_ctr[0] : 0.f;
            val.y = ok ? pp[1] - s_ctr[1] : 0.f;
            val.z = ok ? pp[2] - s_ctr[2] : 0.f;
            val.w = 0.f;
        }
        ((float4*)&F[k][0])[q] = val;
    }
    __syncthreads();

    // layer 1: H[k][j] = relu(B1[j] + F[k]·W1[:,j])
    {
        constexpr int STR = 256 / C1;
        const int j  = t % C1;
        const int kb = t / C1;
        float w1c[68];
#pragma unroll
        for (int i = 0; i < 67; ++i) w1c[i] = W1[i * C1 + j];
        w1c[67] = 0.f;
        const float bj = B1[j];
        for (int k = kb; k < K; k += STR) {
            float acc = bj;
            const float4* fr = (const float4*)&F[k][0];
#pragma unroll
            for (int q = 0; q < 17; ++q) {
                float4 f = fr[q];
                acc = fmaf(f.x, w1c[4 * q + 0], acc);
                acc = fmaf(f.y, w1c[4 * q + 1], acc);
                acc = fmaf(f.z, w1c[4 * q + 2], acc);
                acc = fmaf(f.w, w1c[4 * q + 3], acc);
            }
            H[k][j] = fmaxf(acc, 0.f);
        }
    }
    __syncthreads();

    // layer 2 + masked max over neighbors
    if constexpr (C2 == 256) {
        const int j2 = t;
        float w2c[C1];
#pragma unroll
        for (int i = 0; i < C1; ++i) w2c[i] = W2[i * C2 + j2];
        const float bj = B2[j2];
        float omax = NEGV;
        for (int k = 0; k < K; ++k) {
            if (!s_valid[k]) continue;          // uniform branch
            float acc = bj;
            const float4* hr = (const float4*)&H[k][0];
#pragma unroll
            for (int q = 0; q < C1 / 4; ++q) {
                float4 h = hr[q];
                acc = fmaf(h.x, w2c[4 * q + 0], acc);
                acc = fmaf(h.y, w2c[4 * q + 1], acc);
                acc = fmaf(h.z, w2c[4 * q + 2], acc);
                acc = fmaf(h.w, w2c[4 * q + 3], acc);
            }
            omax = fmaxf(omax, fmaxf(acc, 0.f));
        }
        out[c * 384 + OUTOFF + j2] = omax;
    } else {
        // C2 == 128: 2 thread-groups split the k range, combine via LDS
        const int j2 = t % C2;
        const int g  = t / C2;
        __shared__ float pm[256];
        float w2c[C1];
#pragma unroll
        for (int i = 0; i < C1; ++i) w2c[i] = W2[i * C2 + j2];
        const float bj = B2[j2];
        float omax = NEGV;
        for (int k = g; k < K; k += 2) {
            if (!s_valid[k]) continue;
            float acc = bj;
            const float4* hr = (const float4*)&H[k][0];
#pragma unroll
            for (int q = 0; q < C1 / 4; ++q) {
                float4 h = hr[q];
                acc = fmaf(h.x, w2c[4 * q + 0], acc);
                acc = fmaf(h.y, w2c[4 * q + 1], acc);
                acc = fmaf(h.z, w2c[4 * q + 2], acc);
                acc = fmaf(h.w, w2c[4 * q + 3], acc);
            }
            omax = fmaxf(omax, fmaxf(acc, 0.f));
        }
        pm[t] = omax;
        __syncthreads();
        if (t < C2) out[c * 384 + OUTOFF + t] = fmaxf(pm[t], pm[t + C2]);
    }
}

extern "C" void kernel_launch(void* const* d_in, const int* in_sizes, int n_in,
                              void* d_out, int out_size, void* d_ws, size_t ws_size,
                              hipStream_t stream) {
    const float* x    = (const float*)d_in[0];
    const float* pos  = (const float*)d_in[1];
    const float* w1_0 = (const float*)d_in[2];
    const float* b1_0 = (const float*)d_in[3];
    const float* w1_1 = (const float*)d_in[4];
    const float* b1_1 = (const float*)d_in[5];
    const float* w2_0 = (const float*)d_in[6];
    const float* b2_0 = (const float*)d_in[7];
    const float* w2_1 = (const float*)d_in[8];
    const float* b2_1 = (const float*)d_in[9];

    float* out   = (float*)d_out;
    float* pos_s = out + NCENT * 384;          // second output, written by FPS

    char* ws = (char*)d_ws;
    int*   ncnt = (int*)ws;                                   // NCENT ints
    int*   nidx = (int*)(ws + NCENT * 4);                     // NCENT*64 ints
    float* nd2  = (float*)(ws + NCENT * 4 + NCENT * KMAX * 4);// NCENT*64 floats

    fps_kernel<<<BATCH, FPS_T, 0, stream>>>(pos, pos_s);
    knn_kernel<<<NCENT, 256, 0, stream>>>(pos, pos_s, nidx, nd2, ncnt);
    mlp_kernel<32, 64, 128, 0><<<NCENT, 256, 0, stream>>>(
        x, pos, pos_s, nidx, nd2, ncnt, w1_0, b1_0, w1_1, b1_1, out, 0.04f);
    mlp_kernel<64, 128, 256, 128><<<NCENT, 256, 0, stream>>>(
        x, pos, pos_s, nidx, nd2, ncnt, w2_0, b2_0, w2_1, b2_1, out, 0.16f);
}